// Round 2
// baseline (578.691 us; speedup 1.0000x reference)
//
#include <hip/hip_runtime.h>
#include <hip/hip_bf16.h>

// Downsample: ternary-quantized conv3x3 stride2 pad1, NCHW.
// x:(32,384,64,64) f32, w:(384,384,3,3) f32, bias:(384,) f32 -> out:(32,384,32,32) f32
// Implicit GEMM: M=32768 (n,oh,ow), N=384 (o), K=3456 ((kh,kw,c)), bf16 MFMA, fp32 alpha/bias epilogue.
//
// DETERMINISM: the harness re-validates d_out after graph-replay timing. Round-1
// failed post-timing only; the lone call-order-dependent value was a float
// atomicAdd reduction for alpha. This version has NO atomics and NO memset —
// the whole pipeline is a bitwise-deterministic pure function of d_in.

#define CIN   384
#define HIN   64
#define WIN   64
#define OHW   32
#define KDIM  3456          // 9*384
#define NWELT 1327104       // 384*384*9
#define MDIM  32768         // 32*32*32
#define OUTN  12582912      // 32*384*32*32

using bf16 = __hip_bfloat16;
typedef __attribute__((ext_vector_type(8))) short short8;   // MFMA A/B frag (8 bf16)
typedef __attribute__((ext_vector_type(4))) float floatx4;  // MFMA C/D frag
typedef __attribute__((ext_vector_type(4))) unsigned short ushort4v;

// ws layout (floats): [0]=alpha, [1]=thr, [2..64)=62 partial sums  (bytes [0,256))
// bytes [256, 256+100663296): x_nhwc bf16 [32][64][64][384]
// bytes [256+100663296, +2654208): Wq bf16 [384][3456] (k=(kh*3+kw)*384+c)
// WS_NEED identical to round-1 (proven sufficient: round-1 validation ran the MFMA path).
#define NPART  62
#define XN_OFF 256
#define WQ_OFF (256 + 100663296)

// ---- Stage 1: fixed-slot partial sums of |w| (no atomics -> deterministic) ----
__global__ void absum_part(const float* __restrict__ w, float* __restrict__ ws) {
    const float4* w4 = (const float4*)w;
    float s = 0.f;
    for (int i = blockIdx.x * 256 + threadIdx.x; i < NWELT / 4; i += NPART * 256) {
        float4 v = w4[i];
        s += fabsf(v.x) + fabsf(v.y) + fabsf(v.z) + fabsf(v.w);
    }
    for (int off = 32; off; off >>= 1) s += __shfl_down(s, off, 64);
    __shared__ float red[4];
    if ((threadIdx.x & 63) == 0) red[threadIdx.x >> 6] = s;
    __syncthreads();
    if (threadIdx.x == 0) ws[2 + blockIdx.x] = red[0] + red[1] + red[2] + red[3];
}

// ---- Stage 2: fixed-order final reduction; store alpha and thr once ----
__global__ void absum_final(float* __restrict__ ws) {
    if (threadIdx.x == 0) {
        float s = 0.f;
        for (int i = 0; i < NPART; ++i) s += ws[2 + i];
        float alpha = s * (1.0f / NWELT);
        ws[0] = alpha;
        ws[1] = 1e-3f * alpha;
    }
}

// ---- Ternary quantize + permute weights to [o][k], k=(kh*3+kw)*384+c ----
__global__ void quant_kernel(const float* __restrict__ w, const float* __restrict__ ws,
                             bf16* __restrict__ wq) {
    int i = blockIdx.x * blockDim.x + threadIdx.x;
    if (i >= NWELT) return;
    float thr = ws[1];
    float v = w[i];
    float q = (v > thr) ? 1.f : ((v < -thr) ? -1.f : 0.f);
    // i = ((o*384 + c)*3 + kh)*3 + kw
    int kw = i % 3; int t = i / 3; int kh = t % 3; t /= 3; int c = t % 384; int o = t / 384;
    wq[o * KDIM + (kh * 3 + kw) * 384 + c] = __float2bfloat16(q);
}

// ---- NCHW f32 -> NHWC bf16. Block: 64c x 64w for one (n,h). grid=(2048, 6). ----
// float4 coalesced reads; short8 (16B) coalesced-ish writes (128B chunks).
__global__ void nhwc_kernel(const float* __restrict__ x, bf16* __restrict__ xn) {
    int nh = blockIdx.x;
    int n = nh >> 6, h = nh & 63;
    int c0 = blockIdx.y * 64;
    __shared__ bf16 tile[64][76];   // 76: 8B-aligned vec stores, bank-spread columns
    const float* src = x + ((n * CIN + c0) * HIN + h) * WIN;  // c-row stride 4096 floats
    for (int i = 0; i < 4; ++i) {
        int s = threadIdx.x + i * 256;     // [0,1024): 64c x 16 float4
        int cl = s >> 4, w4 = (s & 15) * 4;
        float4 v = *(const float4*)(src + cl * 4096 + w4);
        bf16 t4[4];
        t4[0] = __float2bfloat16(v.x); t4[1] = __float2bfloat16(v.y);
        t4[2] = __float2bfloat16(v.z); t4[3] = __float2bfloat16(v.w);
        *(ushort4v*)&tile[cl][w4] = *(ushort4v*)t4;   // 8B aligned: (cl*76+w4)*2 % 8 == 0
    }
    __syncthreads();
    bf16* dst = xn + ((size_t)(n * HIN + h) * WIN) * CIN + c0;
    for (int i = 0; i < 2; ++i) {
        int q = threadIdx.x + i * 256;     // [0,512): 64w x 8 c-octets
        int wc = q >> 3, c8 = (q & 7) * 8;
        bf16 tmp[8];
        #pragma unroll
        for (int j = 0; j < 8; ++j) tmp[j] = tile[c8 + j][wc];
        *(short8*)(dst + (size_t)wc * CIN + c8) = *(short8*)tmp;
    }
}

// ---- GEMM: D[o][m] = sum_k Wq[o][k] * X[m][k]. A=Wq, B=X. ----
// BM=128 (m), BNO=128 (o), BK=64. 4 waves, each 64x64 (4x4 frags of 16x16x32).
#define BM  128
#define BNO 128
#define BK  64
#define LDK 72   // padded LDS k-stride: 144B row stride -> <=2-way bank alias (free)

__global__ __launch_bounds__(256) void conv_gemm(const bf16* __restrict__ xn,
                                                 const bf16* __restrict__ wq,
                                                 const float* __restrict__ ws,
                                                 const float* __restrict__ bias,
                                                 float* __restrict__ out) {
    int m_base = blockIdx.x * BM;   // 256 tiles
    int o_base = blockIdx.y * BNO;  // 3 tiles
    __shared__ __align__(16) bf16 lW[BNO * LDK];
    __shared__ __align__(16) bf16 lX[BM * LDK];
    int tid = threadIdx.x;
    int lane = tid & 63;
    int wv = tid >> 6;
    int wo = (wv & 1) * 64;   // wave o-offset in tile
    int wm = (wv >> 1) * 64;  // wave m-offset in tile

    floatx4 acc[4][4];
    for (int i = 0; i < 4; ++i)
        for (int j = 0; j < 4; ++j)
            acc[i][j] = (floatx4){0.f, 0.f, 0.f, 0.f};

    for (int kb = 0; kb < KDIM / BK; ++kb) {          // 54 rounds
        int khkw = kb / 6;
        int c0 = (kb % 6) * 64;
        int kh = khkw / 3, kw = khkw % 3;
        const bf16* wsrc = wq + o_base * KDIM + khkw * 384 + c0;
        for (int i = 0; i < 4; ++i) {
            int s = tid + i * 256;
            int r = s >> 3, l8 = s & 7;
            short8 v = *(const short8*)(wsrc + r * KDIM + l8 * 8);
            *(short8*)(&lW[r * LDK + l8 * 8]) = v;
        }
        for (int i = 0; i < 4; ++i) {
            int s = tid + i * 256;
            int r = s >> 3, l8 = s & 7;
            int m = m_base + r;
            int n = m >> 10, oh = (m >> 5) & 31, ow = m & 31;
            int ih = 2 * oh - 1 + kh, iw = 2 * ow - 1 + kw;  // max 63, only -1 can be OOB
            short8 v = (short8){0, 0, 0, 0, 0, 0, 0, 0};
            if (ih >= 0 && iw >= 0)
                v = *(const short8*)(xn + ((n * HIN + ih) * WIN + iw) * CIN + c0 + l8 * 8);
            *(short8*)(&lX[r * LDK + l8 * 8]) = v;
        }
        __syncthreads();
        for (int ks = 0; ks < 2; ++ks) {
            int koff = ks * 32 + (lane >> 4) * 8;
            short8 af[4], bfr[4];
            for (int i = 0; i < 4; ++i)
                af[i] = *(const short8*)(&lW[(wo + i * 16 + (lane & 15)) * LDK + koff]);
            for (int j = 0; j < 4; ++j)
                bfr[j] = *(const short8*)(&lX[(wm + j * 16 + (lane & 15)) * LDK + koff]);
            for (int i = 0; i < 4; ++i)
                for (int j = 0; j < 4; ++j)
                    acc[i][j] = __builtin_amdgcn_mfma_f32_16x16x32_bf16(af[i], bfr[j], acc[i][j], 0, 0, 0);
        }
        __syncthreads();
    }

    // epilogue: D row=(lane>>4)*4+reg = o, col=lane&15 = m -> coalesced along ow
    float alpha = ws[0];
    int quad = lane >> 4, colm = lane & 15;
    for (int i = 0; i < 4; ++i) {
        for (int j = 0; j < 4; ++j) {
            int mm = m_base + wm + j * 16 + colm;
            int n = mm >> 10, oh = (mm >> 5) & 31, ow = mm & 31;
            for (int r = 0; r < 4; ++r) {
                int o = o_base + wo + i * 16 + quad * 4 + r;
                out[((n * 384 + o) * OHW + oh) * OHW + ow] = alpha * acc[i][j][r] + bias[o];
            }
        }
    }
}

extern "C" void kernel_launch(void* const* d_in, const int* in_sizes, int n_in,
                              void* d_out, int out_size, void* d_ws, size_t ws_size,
                              hipStream_t stream) {
    (void)in_sizes; (void)n_in; (void)out_size; (void)ws_size;
    const float* x    = (const float*)d_in[0];
    const float* w    = (const float*)d_in[1];
    const float* bias = (const float*)d_in[2];
    float* out = (float*)d_out;
    float* wsf = (float*)d_ws;
    bf16* xn = (bf16*)((char*)d_ws + XN_OFF);
    bf16* wq = (bf16*)((char*)d_ws + WQ_OFF);

    absum_part<<<NPART, 256, 0, stream>>>(w, wsf);
    absum_final<<<1, 64, 0, stream>>>(wsf);
    quant_kernel<<<(NWELT + 255) / 256, 256, 0, stream>>>(w, wsf, wq);
    nhwc_kernel<<<dim3(2048, 6), 256, 0, stream>>>(x, xn);
    conv_gemm<<<dim3(MDIM / BM, 384 / BNO), 256, 0, stream>>>(xn, wq, wsf, bias, out);
}

// Round 3
// 428.295 us; speedup vs baseline: 1.3511x; 1.3511x over previous
//
#include <hip/hip_runtime.h>
#include <hip/hip_bf16.h>

// Downsample: ternary-quantized conv3x3 stride2 pad1, NCHW.
// x:(32,384,64,64) f32, w:(384,384,3,3) f32, bias:(384,) f32 -> out:(32,384,32,32) f32
// Implicit GEMM: M=32768 (n,oh,ow), N=384 (o), K=3456 ((kh,kw,c)), bf16 MFMA.
// Round 3: conv_gemm staged via global_load_lds (16B DMA) with XOR-swizzled LDS
// (no padding - DMA dest is wave-uniform base + lane*16). Conv padding rows are
// DMA'd from a 16B zero region in ws (global addr is per-lane). Deterministic:
// no atomics anywhere.

#define CIN   384
#define HIN   64
#define WIN   64
#define OHW   32
#define KDIM  3456          // 9*384
#define NWELT 1327104       // 384*384*9
#define MDIM  32768         // 32*32*32

using bf16 = __hip_bfloat16;
typedef __attribute__((ext_vector_type(8))) short short8;   // MFMA A/B frag (8 bf16)
typedef __attribute__((ext_vector_type(4))) float floatx4;  // MFMA C/D frag
typedef __attribute__((ext_vector_type(2))) unsigned short ushort2v;

#define AS1 __attribute__((address_space(1)))
#define AS3 __attribute__((address_space(3)))
#define DMA16(g, l) __builtin_amdgcn_global_load_lds((const AS1 void*)(g), (AS3 void*)(l), 16, 0, 0)

// ws layout (floats): [0]=alpha, [1]=thr, [2..64)=62 partials; f[16..20) is
// REUSED as a 16B zero region (written by absum_final AFTER consuming partials).
// bytes [256, 256+100663296): x_nhwc bf16 [32][64][64][384]
// bytes [256+100663296, +2654208): Wq bf16 [384][3456] (k=(kh*3+kw)*384+c)
#define NPART  62
#define ZG_F   16
#define XN_OFF 256
#define WQ_OFF (256 + 100663296)

// ---- Stage 1: fixed-slot partial sums of |w| (no atomics -> deterministic) ----
__global__ void absum_part(const float* __restrict__ w, float* __restrict__ ws) {
    const float4* w4 = (const float4*)w;
    float s = 0.f;
    for (int i = blockIdx.x * 256 + threadIdx.x; i < NWELT / 4; i += NPART * 256) {
        float4 v = w4[i];
        s += fabsf(v.x) + fabsf(v.y) + fabsf(v.z) + fabsf(v.w);
    }
    for (int off = 32; off; off >>= 1) s += __shfl_down(s, off, 64);
    __shared__ float red[4];
    if ((threadIdx.x & 63) == 0) red[threadIdx.x >> 6] = s;
    __syncthreads();
    if (threadIdx.x == 0) ws[2 + blockIdx.x] = red[0] + red[1] + red[2] + red[3];
}

// ---- Stage 2: fixed-order final reduction; also zero the DMA guard region ----
__global__ void absum_final(float* __restrict__ ws) {
    if (threadIdx.x == 0) {
        float s = 0.f;
        for (int i = 0; i < NPART; ++i) s += ws[2 + i];
        float alpha = s * (1.0f / NWELT);
        ws[0] = alpha;
        ws[1] = 1e-3f * alpha;
        ws[ZG_F + 0] = 0.f; ws[ZG_F + 1] = 0.f;   // 16B zero guard (partials dead now)
        ws[ZG_F + 2] = 0.f; ws[ZG_F + 3] = 0.f;
    }
}

// ---- Ternary quantize, output-indexed (coalesced 2B writes; reads are L2/L3-hot) ----
__global__ void quant_kernel(const float* __restrict__ w, const float* __restrict__ ws,
                             bf16* __restrict__ wq) {
    int j = blockIdx.x * 256 + threadIdx.x;   // j = o*3456 + (kh*3+kw)*384 + c
    if (j >= NWELT) return;
    float thr = ws[1];
    int o = j / KDIM;
    int rmd = j - o * KDIM;
    int khkw = rmd / 384;
    int c = rmd - khkw * 384;
    float v = w[((o * 384 + c) * 9) + khkw];
    float q = (v > thr) ? 1.f : ((v < -thr) ? -1.f : 0.f);
    wq[j] = __float2bfloat16(q);
}

// ---- NCHW f32 -> NHWC bf16. Block: 64c x 64w for one (n,h). grid=(2048, 6). ----
__global__ void nhwc_kernel(const float* __restrict__ x, bf16* __restrict__ xn) {
    int nh = blockIdx.x;
    int n = nh >> 6, h = nh & 63;
    int c0 = blockIdx.y * 64;
    __shared__ bf16 tile[64][66];   // stride 66: column reads ~conflict-free (33c banks)
    const float* src = x + ((n * CIN + c0) * HIN + h) * WIN;  // c-row stride 4096 floats
    for (int i = 0; i < 4; ++i) {
        int s = threadIdx.x + i * 256;     // [0,1024): 64c x 16 float4
        int cl = s >> 4, w4 = (s & 15) * 4;
        float4 v = *(const float4*)(src + cl * 4096 + w4);
        bf16 t0[2], t1[2];
        t0[0] = __float2bfloat16(v.x); t0[1] = __float2bfloat16(v.y);
        t1[0] = __float2bfloat16(v.z); t1[1] = __float2bfloat16(v.w);
        *(ushort2v*)&tile[cl][w4]     = *(ushort2v*)t0;   // 4B aligned
        *(ushort2v*)&tile[cl][w4 + 2] = *(ushort2v*)t1;
    }
    __syncthreads();
    bf16* dst = xn + ((size_t)(n * HIN + h) * WIN) * CIN + c0;
    for (int i = 0; i < 2; ++i) {
        int q = threadIdx.x + i * 256;     // [0,512): 64w x 8 c-octets
        int wc = q >> 3, c8 = (q & 7) * 8;
        bf16 tmp[8];
        #pragma unroll
        for (int j = 0; j < 8; ++j) tmp[j] = tile[c8 + j][wc];
        *(short8*)(dst + (size_t)wc * CIN + c8) = *(short8*)tmp;
    }
}

// ---- GEMM: D[o][m] = sum_k Wq[o][k] * X[m][k]. A=Wq, B=X. ----
// BM=128 (m), BNO=128 (o), BK=64. 4 waves, each 64x64 (4x4 frags of 16x16x32).
// LDS layout (per buffer, 128 rows x 64 k-elements, unpadded 128B rows):
//   slot(r, oct) at bytes r*128 + oct*16 holds global octet (oct ^ (r&7)) of row r.
// DMA coverage: call (wv,i) covers slots (wv*4+i)*64 + lane; lane's global octet
//   g = (lane&7) ^ (lane>>3), row r = (wv*4+i)*8 + (lane>>3).
// ds_read side: octet g of row r lives at oct = g ^ (r&7); with r = ..+(lane&15)
//   this folds to oct = (ks*4 + quad) ^ (lane&7)  -> <=2-way bank alias (free).
#define BM  128
#define BNO 128

__global__ __launch_bounds__(256) void conv_gemm(const bf16* __restrict__ xn,
                                                 const bf16* __restrict__ wq,
                                                 const float* __restrict__ ws,
                                                 const float* __restrict__ bias,
                                                 float* __restrict__ out,
                                                 const bf16* __restrict__ zg) {
    int m_base = blockIdx.x * BM;   // 256 tiles
    int o_base = blockIdx.y * BNO;  // 3 tiles
    __shared__ __align__(16) bf16 lW[BNO * 64];
    __shared__ __align__(16) bf16 lX[BM * 64];
    int tid = threadIdx.x;
    int lane = tid & 63;
    int wv = tid >> 6;
    int wo = (wv & 1) * 64;
    int wm = (wv >> 1) * 64;

    // per-thread fixed staging descriptors
    int g = (lane & 7) ^ (lane >> 3);          // global octet this lane DMAs
    const bf16* pw[4];
    const bf16* pxn[4];
    int oh2[4], ow2[4];
    bf16* ldsWb[4]; bf16* ldsXb[4];
    #pragma unroll
    for (int i = 0; i < 4; ++i) {
        int r = (wv * 4 + i) * 8 + (lane >> 3);          // row in tile [0,128)
        ldsWb[i] = &lW[(wv * 4 + i) * 512];              // wave-uniform 16B-slot base
        ldsXb[i] = &lX[(wv * 4 + i) * 512];
        pw[i] = wq + (size_t)(o_base + r) * KDIM + g * 8;
        int m = m_base + r;
        int n = m >> 10, oh = (m >> 5) & 31, ow = m & 31;
        pxn[i] = xn + (size_t)n * (HIN * WIN * CIN) + g * 8;
        oh2[i] = 2 * oh - 1;
        ow2[i] = 2 * ow - 1;
    }

    floatx4 acc[4][4];
    for (int i = 0; i < 4; ++i)
        for (int j = 0; j < 4; ++j)
            acc[i][j] = (floatx4){0.f, 0.f, 0.f, 0.f};

    for (int khkw = 0; khkw < 9; ++khkw) {
        int kh = khkw / 3, kw = khkw % 3;
        const bf16* pwk[4];
        const bf16* pxk[4];
        #pragma unroll
        for (int i = 0; i < 4; ++i) {
            pwk[i] = pw[i] + khkw * 384;
            int ih = oh2[i] + kh, iw = ow2[i] + kw;      // upper bound fine (<=63)
            bool valid = (ih >= 0) & (iw >= 0);
            pxk[i] = valid ? pxn[i] + (ih * WIN + iw) * CIN : (const bf16*)0;
        }
        for (int cc = 0; cc < 6; ++cc) {
            int coff = cc * 64;
            #pragma unroll
            for (int i = 0; i < 4; ++i)
                DMA16(pwk[i] + coff, ldsWb[i]);
            #pragma unroll
            for (int i = 0; i < 4; ++i) {
                const bf16* p = pxk[i] ? pxk[i] + coff : zg;
                DMA16(p, ldsXb[i]);
            }
            __syncthreads();
            #pragma unroll
            for (int ks = 0; ks < 2; ++ks) {
                int oct = ((ks * 4 + (lane >> 4)) ^ (lane & 7)) * 8;
                short8 af[4], bfr[4];
                #pragma unroll
                for (int i = 0; i < 4; ++i)
                    af[i] = *(const short8*)(&lW[(wo + i * 16 + (lane & 15)) * 64 + oct]);
                #pragma unroll
                for (int j = 0; j < 4; ++j)
                    bfr[j] = *(const short8*)(&lX[(wm + j * 16 + (lane & 15)) * 64 + oct]);
                #pragma unroll
                for (int i = 0; i < 4; ++i)
                    #pragma unroll
                    for (int j = 0; j < 4; ++j)
                        acc[i][j] = __builtin_amdgcn_mfma_f32_16x16x32_bf16(af[i], bfr[j], acc[i][j], 0, 0, 0);
            }
            __syncthreads();
        }
    }

    // epilogue: D row=(lane>>4)*4+reg = o, col=lane&15 = m -> coalesced along ow
    float alpha = ws[0];
    int quad = lane >> 4, colm = lane & 15;
    for (int i = 0; i < 4; ++i) {
        for (int j = 0; j < 4; ++j) {
            int mm = m_base + wm + j * 16 + colm;
            int n = mm >> 10, oh = (mm >> 5) & 31, ow = mm & 31;
            for (int r = 0; r < 4; ++r) {
                int o = o_base + wo + i * 16 + quad * 4 + r;
                out[((n * 384 + o) * OHW + oh) * OHW + ow] = alpha * acc[i][j][r] + bias[o];
            }
        }
    }
}

extern "C" void kernel_launch(void* const* d_in, const int* in_sizes, int n_in,
                              void* d_out, int out_size, void* d_ws, size_t ws_size,
                              hipStream_t stream) {
    (void)in_sizes; (void)n_in; (void)out_size; (void)ws_size;
    const float* x    = (const float*)d_in[0];
    const float* w    = (const float*)d_in[1];
    const float* bias = (const float*)d_in[2];
    float* out = (float*)d_out;
    float* wsf = (float*)d_ws;
    bf16* xn = (bf16*)((char*)d_ws + XN_OFF);
    bf16* wq = (bf16*)((char*)d_ws + WQ_OFF);
    const bf16* zg = (const bf16*)(wsf + ZG_F);

    absum_part<<<NPART, 256, 0, stream>>>(w, wsf);
    absum_final<<<1, 64, 0, stream>>>(wsf);
    quant_kernel<<<(NWELT + 255) / 256, 256, 0, stream>>>(w, wsf, wq);
    nhwc_kernel<<<dim3(2048, 6), 256, 0, stream>>>(x, xn);
    conv_gemm<<<dim3(MDIM / BM, 384 / BNO), 256, 0, stream>>>(xn, wq, wsf, bias, out, zg);
}